// Round 13
// baseline (1014.963 us; speedup 1.0000x reference)
//
#include <hip/hip_runtime.h>

using u64 = unsigned long long;
typedef __attribute__((ext_vector_type(8))) short vshort8;

// ---------------------------------------------------------------------------
// CIFAR10 BinaryNet, f32-faithful edition (R20 resubmit: halo occupancy probe
// (256,3) -> (256,6); previous round hit GPUAcquisitionTimeout, no data).
// Correctness contract (R4-R19 passed absmax 0.0): replicate the np-f32
// reference bit-exactly where signs are decided:
//  * bin_act/bin_w literally: rint(clip((x+1)/2,0,1)) != 0, f32, half-even
//  * conv1: f32 accumulation in (ci,ky,kx) sequential order + bias in f32
//  * binary layers: exact integer dot (XOR+POPCNT), order-independent
//  * BN mean/var: numpy reduction replicated; bn chain in f32
// R19 POST-MORTEM: total 1005.3 (best). L6 bank-swizzle CONFIRMED (pred gone
// from top-5); R18 tail changes confirmed keepers. Top-5 now exclusively L2
// halo @ 96us, VALUBusy 83-85%, Occupancy 47%. Budget per wave ~6.1k insts
// vs ~2.5k core => 2.4x bloat AND 15% unissued cycles. R20 tests the
// latency-gap hypothesis SAFELY: (256,3)->(256,6) raises the occupancy cap
// (12->24 waves/CU; LDS permits 8 blocks) with VGPR budget 85 > the
// compiler's freely-chosen 48 -> cannot induce the R7/R10 squeeze-spill.
// Single variable, all four halo layers. Null result (dur flat) closes the
// occupancy axis: conv_bin is then issue-saturated instruction-bound.
// Tripwires: halo VGPR < 48 or FETCH > 10 MB => revert; absmax stays 0.0.
// Activations packed [n][h][w][C/64] u64, bit c%64 of word c/64 == (+1).
// ---------------------------------------------------------------------------

// literal bin_act / bin_w: returns 1 for +1, 0 for -1
__device__ __forceinline__ int bin01(float x) {
  float u = (x + 1.0f) * 0.5f;
  u = fminf(fmaxf(u, 0.0f), 1.0f);
  return rintf(u) != 0.0f;  // round half-even, tie -> 0 -> -1
}

// ============================ weight packing ===============================
// Block per cout; stage the contiguous Cin*9-float row in LDS (coalesced
// float4), pack words from LDS. Same bin01, bit map, out layout => bit-exact.
__global__ void pack_conv_w2(const float* __restrict__ w, u64* __restrict__ out,
                             int Cin) {
  const int co = blockIdx.x;
  const int t = threadIdx.x;  // 256
  const int nf = Cin * 9;     // <= 4608
  __shared__ float ls[4608];
  const float* wr = w + (size_t)co * nf;
  const int nf4 = nf >> 2;
  for (int i = t; i < nf4; i += 256)
    *reinterpret_cast<float4*>(&ls[i * 4]) =
        *reinterpret_cast<const float4*>(&wr[i * 4]);
  __syncthreads();
  const int cqn = Cin >> 6;
  for (int idx = t; idx < 9 * cqn; idx += 256) {
    const int q = idx % cqn, k = idx / cqn;
    u64 word = 0;
    for (int l = 0; l < 64; ++l)
      if (bin01(ls[(q * 64 + l) * 9 + k])) word |= (1ull << l);
    out[(size_t)co * 9 * cqn + idx] = word;
  }
}

// border-pattern correction table: CT[co][p], p = r*3+c, r/c in {0 none,
// 1 first-row/col invalid, 2 last-row/col invalid}. corr = sum of
// popcount(w) over taps in the invalid set (row-set UNION col-set).
__global__ void pack_corr(const u64* __restrict__ W, int* __restrict__ CT) {
  const int idx = blockIdx.x * 256 + threadIdx.x;  // 14976 total
  const int b1 = 1152, b2 = 3456, b3 = 5760, b4 = 10368, b5 = 14976;
  if (idx >= b5) return;
  int lo, woff, cq;
  if (idx < b1)      { lo = 0;  woff = 0;     cq = 2; }   // L2: 128 co
  else if (idx < b2) { lo = b1; woff = 2304;  cq = 2; }   // L3: 256 co
  else if (idx < b3) { lo = b2; woff = 6912;  cq = 4; }   // L4: 256 co
  else if (idx < b4) { lo = b3; woff = 16128; cq = 4; }   // L5: 512 co
  else               { lo = b4; woff = 34560; cq = 8; }   // L6: 512 co
  const int rel = idx - lo;
  const int co = rel / 9, p = rel % 9;
  const int r = p / 3, c = p % 3;
  int corr = 0;
  for (int dy = 0; dy < 3; ++dy)
    for (int dx = 0; dx < 3; ++dx) {
      const bool inv = (r == 1 && dy == 0) || (r == 2 && dy == 2) ||
                       (c == 1 && dx == 0) || (c == 2 && dx == 2);
      if (inv) {
        const u64* wp = W + woff + ((size_t)(co * 9 + dy * 3 + dx)) * cq;
        for (int q = 0; q < cq; ++q) corr += __popcll(wp[q]);
      }
    }
  CT[idx] = corr;
}

__global__ void pack_fc_w(const float* __restrict__ w, u64* __restrict__ out,
                          int Fi, int Fo) {
  const int fiq = Fi >> 6;
  const int total = Fo * fiq;
  const int idx = blockIdx.x * 256 + threadIdx.x;
  if (idx >= total) return;
  const int q = idx % fiq, o = idx / fiq;
  u64 word = 0;
  for (int l = 0; l < 64; ++l)
    if (bin01(w[(size_t)o * Fi + q * 64 + l])) word |= (1ull << l);
  out[idx] = word;
}

// fc1 with NCHW-flatten permutation: f = c*16 + h*4 + w; act word q=(h*4+w)*8+cq
// One o-row (8192 floats, 32 KB) staged in LDS coalesced; 128 threads pack.
__global__ void pack_fc1_w(const float* __restrict__ w, u64* __restrict__ out) {
  const int o = blockIdx.x;  // 1024
  const int t = threadIdx.x; // 256
  __shared__ float ls[8192];
  const float* wr = w + (size_t)o * 8192;
  for (int i = t; i < 2048; i += 256)
    *reinterpret_cast<float4*>(&ls[i * 4]) =
        *reinterpret_cast<const float4*>(&wr[i * 4]);
  __syncthreads();
  if (t < 128) {
    const int q = t, cq = q & 7, hw = q >> 3;
    u64 word = 0;
    for (int l = 0; l < 64; ++l) {
      const int f = (cq * 64 + l) * 16 + hw;
      if (bin01(ls[f])) word |= (1ull << l);
    }
    out[(size_t)o * 128 + q] = word;
  }
}

// conv1 weight signs as +-1.0f floats (k = ci*9+dy*3+dx), for uniform s_load
__global__ void pack_w1f(const float* __restrict__ w1, float* __restrict__ w1f) {
  const int i = blockIdx.x * 256 + threadIdx.x;  // 3456
  if (i < 3456) w1f[i] = bin01(w1[i]) ? 1.0f : -1.0f;
}

// ============================== conv1 (f32) ================================
__device__ __forceinline__ void stage_image(const float* __restrict__ x, int n,
                                            float* __restrict__ xs, int nthreads,
                                            int t) {
  for (int idx = t; idx < 3 * 34 * 34; idx += nthreads) {
    const int ci = idx / 1156, rem = idx % 1156;
    const int hy = rem / 34, wx = rem % 34;
    float v = 0.0f;
    if (hy >= 1 && hy <= 32 && wx >= 1 && wx <= 32)
      v = x[(size_t)n * 3072 + ci * 1024 + (hy - 1) * 32 + (wx - 1)];
    xs[idx] = v;
  }
}

// eval + leaf-sum kernel. block = (n, quarter q); thread = position p (256).
template <int PASS>
__global__ void conv1_eval(const float* __restrict__ x,
                           const float* __restrict__ w1f,
                           const float* __restrict__ cb,
                           const float* __restrict__ st,
                           float* __restrict__ BL) {
  const int blk = blockIdx.x;  // n*4 + q
  const int n = blk >> 2, q = blk & 3;
  const int t = threadIdx.x;   // 256
  __shared__ float xs[3 * 34 * 34];
  __shared__ float yl[256 * 8];    // [p][j8]
  __shared__ float rl[2 * 8 * 8];  // [L][c8][j]
  stage_image(x, n, xs, 256, t);
  __syncthreads();
  const int hw = q * 256 + t;
  const int h = hw >> 5, w = hw & 31;
  float win[27];
#pragma unroll
  for (int k = 0; k < 27; ++k) {
    const int ci = k / 9, dy = (k % 9) / 3, dx = k % 3;
    win[k] = xs[ci * 1156 + (h + dy) * 34 + (w + dx)];
  }
  for (int cc = 0; cc < 16; ++cc) {  // 8 channels per chunk
    float y8[8];
#pragma unroll
    for (int j8 = 0; j8 < 8; ++j8) {
      const int c = cc * 8 + j8;
      const float* wp = w1f + c * 27;
      float acc = 0.0f;
#pragma unroll
      for (int k = 0; k < 27; ++k) acc = fmaf(wp[k], win[k], acc);
      float y = acc + cb[c];
      if (PASS) { const float d = y - st[2 * c]; y = d * d; }
      y8[j8] = y;
    }
    __syncthreads();  // previous chunk's readers done
#pragma unroll
    for (int j8 = 0; j8 < 8; ++j8) yl[t * 8 + j8] = y8[j8];
    __syncthreads();
    if (t < 128) {  // numpy 8-accumulator pass: r = sum_i y[i*8+j], i sequential
      const int L = t >> 6, j = (t >> 3) & 7, c8 = t & 7;
      float r = yl[(L * 128 + j) * 8 + c8];
      for (int i = 1; i < 16; ++i) r += yl[(L * 128 + i * 8 + j) * 8 + c8];
      rl[(L * 8 + c8) * 8 + j] = r;
    }
    __syncthreads();
    if (t < 16) {  // 8-way tree combine, write leaf sum
      const int L = t >> 3, c8 = t & 7;
      const float* p = rl + (L * 8 + c8) * 8;
      const float s =
          ((p[0] + p[1]) + (p[2] + p[3])) + ((p[4] + p[5]) + (p[6] + p[7]));
      BL[((size_t)(n * 8) + (q * 2 + L)) * 128 + (cc * 8 + c8)] = s;
    }
  }
}

// leaf-pairwise then batch-sequential combine (numpy multi-axis reduce order).
__global__ void conv1_comb2(const float* __restrict__ BL, float* __restrict__ st,
                            int pass) {
  const int t = threadIdx.x;        // 256
  const int lane = t & 63;
  const int wid = t >> 6;           // 4 waves
  const int c = blockIdx.x * 32 + wid * 8 + (lane & 7);  // 4 blocks -> 128 ch
  const int leaf = lane >> 3;       // 0..7
  const float* base = BL + (size_t)leaf * 128 + c;
  float S = 0.0f;
#pragma unroll 4
  for (int n = 0; n < 256; ++n) {
    const float v = base[(size_t)n * 1024];
    const float a = v + __shfl_xor(v, 8);    // (l0+l1) etc.
    const float b = a + __shfl_xor(a, 16);   // (l0+l1)+(l2+l3)
    const float Ln = b + __shfl_xor(b, 32);  // full 8-way tree
    S = (n == 0) ? Ln : (S + Ln);
  }
  if (leaf == 0) {
    if (pass == 0) st[2 * c] = S / 262144.0f;
    else           st[2 * c + 1] = 1.0f / sqrtf(S / 262144.0f + 1e-4f);
  }
}

// binarize: thread = position; loops all 128 channels with register window,
// packs bits per-thread (bit l of word cq <-> c = cq*64+l).
__global__ void conv1_binz(const float* __restrict__ x,
                           const float* __restrict__ w1f,
                           const float* __restrict__ cb,
                           const float* __restrict__ st,
                           const float* __restrict__ g,
                           const float* __restrict__ be,
                           u64* __restrict__ out) {
  const int blk = blockIdx.x;  // n*4 + q
  const int n = blk >> 2, q = blk & 3;
  const int t = threadIdx.x;   // 256
  __shared__ float xs[3 * 34 * 34];
  stage_image(x, n, xs, 256, t);
  __syncthreads();
  const int hw = q * 256 + t;
  const int h = hw >> 5, w = hw & 31;
  float win[27];
#pragma unroll
  for (int k = 0; k < 27; ++k) {
    const int ci = k / 9, dy = (k % 9) / 3, dx = k % 3;
    win[k] = xs[ci * 1156 + (h + dy) * 34 + (w + dx)];
  }
  u64 m0 = 0, m1 = 0;
  for (int c = 0; c < 128; ++c) {
    const float* wp = w1f + c * 27;
    float acc = 0.0f;
#pragma unroll
    for (int k = 0; k < 27; ++k) acc = fmaf(wp[k], win[k], acc);
    const float y = acc + cb[c];
    const float tv = ((y - st[2 * c]) * st[2 * c + 1]) * g[c] + be[c];
    const u64 bit = (u64)bin01(tv);
    if (c < 64) m0 |= bit << c;
    else        m1 |= bit << (c - 64);
  }
  u64* dst = out + ((size_t)(n * 1024 + hw)) * 2;
  dst[0] = m0;
  dst[1] = m1;
}

// ================== halo zeroing helper (conv_bin_halo) ====================
template <int CQ, int H>
__device__ __forceinline__ void zero_halo(u64* __restrict__ xs, int t) {
  constexpr int HP = H + 2;
  constexpr int HALO = 2 * HP * CQ + 2 * H * CQ;
  for (int j = t; j < HALO; j += 256) {
    int widx;
    if (j < HP * CQ) widx = j;                                  // row 0
    else if (j < 2 * HP * CQ) widx = (H + 1) * HP * CQ + (j - HP * CQ);  // row H+1
    else {
      const int r = j - 2 * HP * CQ;          // 0 .. 2*H*CQ-1
      const int row = (r / (2 * CQ)) + 1;     // 1..H (2*CQ pow2 -> shift)
      const int s = r & (2 * CQ - 1);
      const int col = (s < CQ) ? 0 : (HP - 1);
      widx = (row * HP + col) * CQ + (s & (CQ - 1));
    }
    xs[widx] = 0;
  }
}

// ================= binary conv, halo variant (L2-L5 only) ==================
// Zero-halo LDS tile, unconditional bcnt-accumulate, CT-corrected integer dot
// (exact). R20: launch_bounds (256,6) -- occupancy cap 12->24 waves/CU.
// VGPR budget 85 > compiler-chosen 48 => no squeeze-spill possible.
template <int CQ, int POOL, int H, int COUT, int NCPB>
__launch_bounds__(256, 6)
__global__ void conv_bin_halo(const u64* __restrict__ xin, const u64* __restrict__ wpk,
                              const int* __restrict__ ct, short* __restrict__ pre) {
  constexpr int OH = H / POOL;
  constexpr int PLANE = OH * OH;
  constexpr int G = 256 / PLANE;
  constexpr int NE = POOL * POOL;
  constexpr int HP = H + 2;
  constexpr int NWP = HP * HP * CQ;
  constexpr int QC = (CQ > 4) ? 4 : CQ;
  constexpr int NQC = CQ / QC;
  constexpr int IW = H * H * CQ;   // interior word count
  constexpr int VEC = IW / 256;    // words per thread (8/2/4/1), VEC | CQ*H
  const int n = blockIdx.x;
  const int t = threadIdx.x;
  __shared__ __align__(16) u64 xs[NWP];
  const u64* src = xin + (size_t)n * IW;
  {
    const int i0 = t * VEC;
    const int q0 = i0 & (CQ - 1);
    const int w0 = (i0 / CQ) & (H - 1);
    const int h0 = i0 / (CQ * H);
    const int dst0 = ((h0 + 1) * HP + (w0 + 1)) * CQ + q0;
    if constexpr (VEC >= 2) {
      ulonglong2 tmp[VEC / 2];
#pragma unroll
      for (int v = 0; v < VEC / 2; ++v)
        tmp[v] = *reinterpret_cast<const ulonglong2*>(&src[i0 + 2 * v]);
      zero_halo<CQ, H>(xs, t);  // overlaps with in-flight loads
#pragma unroll
      for (int v = 0; v < VEC / 2; ++v)
        *reinterpret_cast<ulonglong2*>(&xs[dst0 + 2 * v]) = tmp[v];
    } else {
      const u64 tv = src[i0];
      zero_halo<CQ, H>(xs, t);
      xs[dst0] = tv;
    }
  }
  __syncthreads();
  int cosub;
  if constexpr (PLANE >= 64) cosub = __builtin_amdgcn_readfirstlane(t / PLANE);
  else cosub = t / PLANE;
  const int pos = t % PLANE;
  const int oh = pos / OH, ow = pos % OH;

  int cbase[NE];
#pragma unroll
  for (int py = 0; py < POOL; ++py)
#pragma unroll
    for (int px = 0; px < POOL; ++px)
      cbase[py * POOL + px] = ((oh * POOL + py) * HP + (ow * POOL + px)) * CQ;

  int pc[NCPB][NE];
#pragma unroll
  for (int cc = 0; cc < NCPB; ++cc)
#pragma unroll
    for (int e = 0; e < NE; ++e) pc[cc][e] = 0;

#pragma unroll
  for (int qc = 0; qc < NQC; ++qc) {
#pragma unroll
    for (int k = 0; k < 9; ++k) {
      const int dy = k / 3, dx = k % 3;
      const int koff = (dy * HP + dx) * CQ + qc * QC;  // compile-time per (k,qc)
      u64 cw[NE][QC];
#pragma unroll
      for (int e = 0; e < NE; ++e) {
        const u64* cp = &xs[cbase[e] + koff];
#pragma unroll
        for (int q = 0; q < QC; ++q) cw[e][q] = cp[q];
      }
#pragma unroll
      for (int cc = 0; cc < NCPB; ++cc) {
        const int co = (blockIdx.y * NCPB + cc) * G + cosub;
        const u64* wp = wpk + ((size_t)co * 9 + k) * CQ + qc * QC;
        u64 w[QC];
#pragma unroll
        for (int q = 0; q < QC; ++q) w[q] = wp[q];
#pragma unroll
        for (int e = 0; e < NE; ++e) {
          int acc = pc[cc][e];
#pragma unroll
          for (int q = 0; q < QC; ++q) acc += __popcll(cw[e][q] ^ w[q]);
          pc[cc][e] = acc;
        }
      }
    }
  }

  int vcnt[NE];
#pragma unroll
  for (int py = 0; py < POOL; ++py) {
#pragma unroll
    for (int px = 0; px < POOL; ++px) {
      int cvn = 0;
#pragma unroll
      for (int dy = 0; dy < 3; ++dy)
#pragma unroll
        for (int dx = 0; dx < 3; ++dx) {
          const int hh = oh * POOL + py + dy - 1, ww = ow * POOL + px + dx - 1;
          cvn += (((unsigned)hh < (unsigned)H) && ((unsigned)ww < (unsigned)H)) ? 1 : 0;
        }
      vcnt[py * POOL + px] = cvn;
    }
  }
  int cofs[NE];
#pragma unroll
  for (int py = 0; py < POOL; ++py)
#pragma unroll
    for (int px = 0; px < POOL; ++px) {
      const int chh = oh * POOL + py, cww = ow * POOL + px;
      const int rr = (chh == 0) ? 1 : ((chh == H - 1) ? 2 : 0);
      const int cl = (cww == 0) ? 1 : ((cww == H - 1) ? 2 : 0);
      cofs[py * POOL + px] = rr * 3 + cl;
    }
#pragma unroll
  for (int cc = 0; cc < NCPB; ++cc) {
    const int co = (blockIdx.y * NCPB + cc) * G + cosub;
    const int* ctp = ct + co * 9;
    int best = -1000000;
#pragma unroll
    for (int e = 0; e < NE; ++e) {
      const int dot = vcnt[e] * (CQ * 64) - 2 * (pc[cc][e] - ctp[cofs[e]]);
      best = dot > best ? dot : best;
    }
    pre[((size_t)(n * COUT + co) * OH + oh) * OH + ow] = (short)best;
  }
}

// ============== binary conv, predicated variant (L6 only) ==================
// R19 swizzle CONFIRMED: group-granular XOR kills the 16-way pos-group
// conflict (1.27e7 -> pred dropped out of top-5). Unchanged this round.
template <int CQ, int POOL, int H, int COUT, int NCPB>
__launch_bounds__(256, 4)
__global__ void conv_bin_pred(const u64* __restrict__ xin, const u64* __restrict__ wpk,
                              short* __restrict__ pre) {
  constexpr int OH = H / POOL;
  constexpr int PLANE = OH * OH;
  constexpr int G = 256 / PLANE;
  constexpr int NE = POOL * POOL;
  constexpr int NW_ = H * H * CQ;
  constexpr int QC = (CQ > 4) ? 4 : CQ;
  constexpr int NQC = CQ / QC;
  constexpr bool SWZ = (CQ == 8 && H == 8 && POOL == 2);  // bit layout assumption
  const int n = blockIdx.x;
  const int t = threadIdx.x;
  __shared__ u64 xs[NW_];
  const u64* src = xin + (size_t)n * NW_;
  for (int i = t; i < NW_; i += 256) {
    int di = i;
    if constexpr (SWZ) {
      const int g = i >> 2;
      const int gs = g ^ ((g >> 5) & 1) ^ (((g >> 2) & 1) << 1);
      di = (gs << 2) | (i & 3);
    }
    xs[di] = src[i];
  }
  __syncthreads();
  const int cosub = t / PLANE;
  const int pos = t % PLANE;
  const int oh = pos / OH, ow = pos % OH;

  int pc[NCPB][NE];
#pragma unroll
  for (int cc = 0; cc < NCPB; ++cc)
#pragma unroll
    for (int e = 0; e < NE; ++e) pc[cc][e] = 0;

#pragma unroll
  for (int qc = 0; qc < NQC; ++qc) {
#pragma unroll
    for (int k = 0; k < 9; ++k) {
      const int dy = k / 3, dx = k % 3;
      u64 cw[NE][QC];
      bool cv[NE];
#pragma unroll
      for (int py = 0; py < POOL; ++py) {
#pragma unroll
        for (int px = 0; px < POOL; ++px) {
          const int hh = oh * POOL + py + dy - 1;
          const int ww = ow * POOL + px + dx - 1;
          const bool v = ((unsigned)hh < (unsigned)H) && ((unsigned)ww < (unsigned)H);
          const int e = py * POOL + px;
          cv[e] = v;
          int base = v ? ((hh * H + ww) * CQ + qc * QC) : 0;
          if constexpr (SWZ) {
            const int g = base >> 2;
            const int gs = g ^ ((g >> 5) & 1) ^ (((g >> 2) & 1) << 1);
            base = gs << 2;  // QC==4: base is group-aligned; q-order preserved
          }
#pragma unroll
          for (int q = 0; q < QC; ++q) cw[e][q] = xs[base + q];
        }
      }
#pragma unroll
      for (int cc = 0; cc < NCPB; ++cc) {
        const int co = (blockIdx.y * NCPB + cc) * G + cosub;
        const u64* wp = wpk + ((size_t)co * 9 + k) * CQ + qc * QC;
        u64 w[QC];
#pragma unroll
        for (int q = 0; q < QC; ++q) w[q] = wp[q];
#pragma unroll
        for (int e = 0; e < NE; ++e) {
          int tp = 0;
#pragma unroll
          for (int q = 0; q < QC; ++q) tp += __popcll(cw[e][q] ^ w[q]);
          pc[cc][e] += cv[e] ? tp : 0;
        }
      }
    }
  }

  int vcnt[NE];
#pragma unroll
  for (int py = 0; py < POOL; ++py) {
#pragma unroll
    for (int px = 0; px < POOL; ++px) {
      int cvn = 0;
#pragma unroll
      for (int dy = 0; dy < 3; ++dy)
#pragma unroll
        for (int dx = 0; dx < 3; ++dx) {
          const int hh = oh * POOL + py + dy - 1, ww = ow * POOL + px + dx - 1;
          cvn += (((unsigned)hh < (unsigned)H) && ((unsigned)ww < (unsigned)H)) ? 1 : 0;
        }
      vcnt[py * POOL + px] = cvn;
    }
  }
#pragma unroll
  for (int cc = 0; cc < NCPB; ++cc) {
    const int co = (blockIdx.y * NCPB + cc) * G + cosub;
    int best = -1000000;
#pragma unroll
    for (int e = 0; e < NE; ++e) {
      const int dot = vcnt[e] * (CQ * 64) - 2 * pc[cc][e];
      best = dot > best ? dot : best;
    }
    pre[((size_t)(n * COUT + co) * OH + oh) * OH + ow] = (short)best;
  }
}

// ======================= BN stats, numpy-faithful ==========================
// short8 vector loads -- the numpy 8-accumulator block is exactly 8
// consecutive shorts; identical adds in identical order => bit-exact.
template <int PASS>
__device__ __forceinline__ float acc8(const short* __restrict__ p, float b, float m,
                                      int start, int len) {
  float r[8];
  const vshort8 v0 = *reinterpret_cast<const vshort8*>(&p[start]);
#pragma unroll
  for (int j = 0; j < 8; ++j) {
    float y = (float)v0[j] + b;
    if (PASS) { const float d = y - m; y = d * d; }
    r[j] = y;
  }
  for (int i = 8; i < len; i += 8) {
    const vshort8 vi = *reinterpret_cast<const vshort8*>(&p[start + i]);
#pragma unroll
    for (int j = 0; j < 8; ++j) {
      float y = (float)vi[j] + b;
      if (PASS) { const float d = y - m; y = d * d; }
      r[j] += y;
    }
  }
  return ((r[0] + r[1]) + (r[2] + r[3])) + ((r[4] + r[5]) + (r[6] + r[7]));
}

template <int PASS>
__device__ __forceinline__ float np_sum_hw(const short* __restrict__ p, float b,
                                           float m, int HW) {
  if (HW == 256) return acc8<PASS>(p, b, m, 0, 128) + acc8<PASS>(p, b, m, 128, 128);
  return acc8<PASS>(p, b, m, 0, HW);  // HW = 16 or 64
}

template <int HW>
__global__ void conv_stats(const short* __restrict__ pre, const float* __restrict__ cb,
                           float* __restrict__ st, int Cout) {
  const int c = blockIdx.x;
  const int n = threadIdx.x;  // 256
  const float b = cb[c];
  const short* p = pre + ((size_t)n * Cout + c) * HW;
  __shared__ float ls[256];
  ls[n] = np_sum_hw<0>(p, b, 0.0f, HW);
  __syncthreads();
  __shared__ float ms;
  if (n == 0) {
    float S = ls[0];
    for (int i = 1; i < 256; ++i) S += ls[i];
    ms = S / (float)(256 * HW);
  }
  __syncthreads();
  const float m = ms;
  __syncthreads();
  ls[n] = np_sum_hw<1>(p, b, m, HW);
  __syncthreads();
  if (n == 0) {
    float S = ls[0];
    for (int i = 1; i < 256; ++i) S += ls[i];
    const float v = S / (float)(256 * HW);
    st[2 * c] = m;
    st[2 * c + 1] = 1.0f / sqrtf(v + 1e-4f);
  }
}

// =========================== binarize 2d / pack ============================
__global__ void bin2d(const short* __restrict__ pre, const float* __restrict__ st,
                      const float* __restrict__ cb, const float* __restrict__ g,
                      const float* __restrict__ be, u64* __restrict__ out,
                      int Cout, int OH) {
  const int CQ = Cout >> 6;
  const int HW = OH * OH;
  const int widx = blockIdx.x * 256 + threadIdx.x;  // (n*CQ+cq)*HW+hw
  const int hw = widx % HW;
  const int r = widx / HW;
  const int cq = r % CQ;
  const int n = r / CQ;
  const short* p = pre + ((size_t)(n * Cout + cq * 64)) * HW + hw;
  u64 mask = 0;
  for (int c = 0; c < 64; ++c) {
    const int ch = cq * 64 + c;
    const float val = (float)p[(size_t)c * HW] + cb[ch];
    const float tv = ((val - st[2 * ch]) * st[2 * ch + 1]) * g[ch] + be[ch];
    mask |= ((u64)bin01(tv)) << c;
  }
  out[((size_t)n * HW + hw) * CQ + cq] = mask;
}

// ================== fc1 activation transpose =========================
__global__ void transpose_act(const u64* __restrict__ a, u64* __restrict__ at) {
  const int widx = blockIdx.x * 256 + threadIdx.x;  // 32768 = 256n x 128q
  const int n = widx >> 7, q = widx & 127;
  at[(size_t)q * 256 + n] = a[widx];
}

// ================================ fc layers ================================
__global__ void fc_layer_t(const u64* __restrict__ at, const u64* __restrict__ wpk,
                           short* __restrict__ pre) {
  const int o = blockIdx.x;   // 1024
  const int n = threadIdx.x;  // 256
  const u64* wp = wpk + (size_t)o * 128;
  int pc = 0;
#pragma unroll 8
  for (int q = 0; q < 128; ++q) pc += __popcll(at[(size_t)q * 256 + n] ^ wp[q]);
  pre[(size_t)n * 1024 + o] = (short)(8192 - 2 * pc);
}

__global__ void fc_layer(const u64* __restrict__ xin, const u64* __restrict__ wpk,
                         short* __restrict__ pre, int FiQ, int Fo) {
  const int o = blockIdx.x;
  const int n = threadIdx.x;  // 256
  const u64* xp = xin + (size_t)n * FiQ;
  const u64* wp = wpk + (size_t)o * FiQ;
  int pc = 0;
  for (int q = 0; q < FiQ; ++q) pc += __popcll(xp[q] ^ wp[q]);
  pre[(size_t)n * Fo + o] = (short)(FiQ * 64 - 2 * pc);
}

__global__ void fc_stats(const short* __restrict__ pre, const float* __restrict__ fb,
                         float* __restrict__ st, int Fo) {
  const int o = blockIdx.x * blockDim.x + threadIdx.x;
  if (o >= Fo) return;
  const float b = fb[o];
  float S = (float)pre[o] + b;
#pragma unroll 8
  for (int n = 1; n < 256; ++n) S += (float)pre[(size_t)n * Fo + o] + b;
  const float m = S / 256.0f;
  float d0 = (float)pre[o] + b - m;
  float V = d0 * d0;
#pragma unroll 8
  for (int n = 1; n < 256; ++n) {
    const float d = (float)pre[(size_t)n * Fo + o] + b - m;
    V += d * d;
  }
  st[2 * o] = m;
  st[2 * o + 1] = 1.0f / sqrtf(V / 256.0f + 1e-4f);
}

__global__ void fc_bin(const short* __restrict__ pre, const float* __restrict__ st,
                       const float* __restrict__ fb, const float* __restrict__ g,
                       const float* __restrict__ be, u64* __restrict__ out, int Fo) {
  const int gid = blockIdx.x * 4 + (threadIdx.x >> 6);
  const int lane = threadIdx.x & 63;
  const int OQ = Fo >> 6;
  const int oq = gid % OQ, n = gid / OQ;
  const int o = oq * 64 + lane;
  const float val = (float)pre[(size_t)n * Fo + o] + fb[o];
  const float tv = ((val - st[2 * o]) * st[2 * o + 1]) * g[o] + be[o];
  const u64 mask = __ballot(bin01(tv));
  if (lane == 0) out[(size_t)n * OQ + oq] = mask;
}

// fc3 layer + stats + output fused into one 1-block kernel. Same popcnt
// integer dot; stats replicate fc_stats' exact sequential-n f32 order; output
// expression identical to fc_out.
__global__ void fc3_fused(const u64* __restrict__ xin, const u64* __restrict__ wpk,
                          const float* __restrict__ fb, const float* __restrict__ g,
                          const float* __restrict__ be, float* __restrict__ out) {
  const int n = threadIdx.x;  // 256
  __shared__ short lpre[2560];
  __shared__ float st[20];
  u64 xw[16];
  const u64* xp = xin + (size_t)n * 16;
#pragma unroll
  for (int q = 0; q < 16; ++q) xw[q] = xp[q];
  for (int o = 0; o < 10; ++o) {
    const u64* wp = wpk + (size_t)o * 16;
    int pc = 0;
#pragma unroll
    for (int q = 0; q < 16; ++q) pc += __popcll(xw[q] ^ wp[q]);
    lpre[n * 10 + o] = (short)(1024 - 2 * pc);
  }
  __syncthreads();
  if (n < 10) {
    const float b = fb[n];
    float S = (float)lpre[n] + b;
    for (int i = 1; i < 256; ++i) S += (float)lpre[i * 10 + n] + b;
    const float m = S / 256.0f;
    float d0 = (float)lpre[n] + b - m;
    float V = d0 * d0;
    for (int i = 1; i < 256; ++i) {
      const float d = (float)lpre[i * 10 + n] + b - m;
      V += d * d;
    }
    st[2 * n] = m;
    st[2 * n + 1] = 1.0f / sqrtf(V / 256.0f + 1e-4f);
  }
  __syncthreads();
  for (int o = 0; o < 10; ++o) {
    const float val = (float)lpre[n * 10 + o] + fb[o];
    out[n * 10 + o] = ((val - st[2 * o]) * st[2 * o + 1]) * g[o] + be[o];
  }
}

// ================================= launch ==================================
extern "C" void kernel_launch(void* const* d_in, const int* in_sizes, int n_in,
                              void* d_out, int out_size, void* d_ws, size_t ws_size,
                              hipStream_t stream) {
  if (n_in < 37) return;
  const float* x = (const float*)d_in[0];
  const float *cw1 = (const float*)d_in[1],  *cb1 = (const float*)d_in[2],  *g1 = (const float*)d_in[3],  *be1 = (const float*)d_in[4];
  const float *cw2 = (const float*)d_in[5],  *cb2 = (const float*)d_in[6],  *g2 = (const float*)d_in[7],  *be2 = (const float*)d_in[8];
  const float *cw3 = (const float*)d_in[9],  *cb3 = (const float*)d_in[10], *g3 = (const float*)d_in[11], *be3 = (const float*)d_in[12];
  const float *cw4 = (const float*)d_in[13], *cb4 = (const float*)d_in[14], *g4 = (const float*)d_in[15], *be4 = (const float*)d_in[16];
  const float *cw5 = (const float*)d_in[17], *cb5 = (const float*)d_in[18], *g5 = (const float*)d_in[19], *be5 = (const float*)d_in[20];
  const float *cw6 = (const float*)d_in[21], *cb6 = (const float*)d_in[22], *g6 = (const float*)d_in[23], *be6 = (const float*)d_in[24];
  const float *fw1 = (const float*)d_in[25], *fb1 = (const float*)d_in[26], *gf1 = (const float*)d_in[27], *bef1 = (const float*)d_in[28];
  const float *fw2 = (const float*)d_in[29], *fb2 = (const float*)d_in[30], *gf2 = (const float*)d_in[31], *bef2 = (const float*)d_in[32];
  const float *fw3 = (const float*)d_in[33], *fb3 = (const float*)d_in[34], *gf3 = (const float*)d_in[35], *bef3 = (const float*)d_in[36];
  float* out = (float*)d_out;

  char* ws = (char*)d_ws;
  if (ws_size < 46137344) return;
  float* ST = (float*)ws;                    // f32 stats (m, 1/sqrt(v+eps)) pairs
  float* W1F = (float*)(ws + 32768);         // conv1 +-1.0f signs, 13824 B
  float* BL = (float*)(ws + 65536);          // conv1 leaf partials [256][8][128], 1 MB
  u64* W = (u64*)(ws + 1179648);             // packed weights, 1752320 B
  u64* A = (u64*)(ws + 2981888);             // packed activations, 9240576 B
  int* CT = (int*)(ws + 12222464);           // border-corr tables, 59904 B
  short* PRE = (short*)(ws + 12582912);      // integer pre-activations (reused)
  u64* AT6 = (u64*)(ws + 33554432);          // fc1 transposed acts, 262144 B
  const int S1 = 0, S2 = 256, S3 = 512, S4 = 1024, S5 = 1536, S6 = 2560;
  const int SF1 = 3584, SF2 = 5632;
  const size_t WC2 = 0, WC3 = 2304, WC4 = 6912, WC5 = 16128, WC6 = 34560;
  const size_t WF1 = 71424, WF2 = 202496, WF3 = 218880;
  const size_t A1 = 0, A2 = 524288, A3 = 655360, A4 = 917504, A5 = 983040;
  const size_t A6 = 1114112, AF1 = 1146880, AF2 = 1150976;
  const int CT2 = 0, CT3 = 1152, CT4 = 3456, CT5 = 5760;

  // pack weights (literal bin_w semantics; block-per-cout LDS-staged)
  pack_w1f<<<14, 256, 0, stream>>>(cw1, W1F);
  pack_conv_w2<<<128, 256, 0, stream>>>(cw2, W + WC2, 128);
  pack_conv_w2<<<256, 256, 0, stream>>>(cw3, W + WC3, 128);
  pack_conv_w2<<<256, 256, 0, stream>>>(cw4, W + WC4, 256);
  pack_conv_w2<<<512, 256, 0, stream>>>(cw5, W + WC5, 256);
  pack_conv_w2<<<512, 256, 0, stream>>>(cw6, W + WC6, 512);
  pack_corr<<<59, 256, 0, stream>>>(W, CT);
  pack_fc1_w<<<1024, 256, 0, stream>>>(fw1, W + WF1);
  pack_fc_w<<<64, 256, 0, stream>>>(fw2, W + WF2, 1024, 1024);
  pack_fc_w<<<1, 256, 0, stream>>>(fw3, W + WF3, 1024, 10);

  // layer 1: position-major f32 conv, numpy-faithful stats, binarize
  conv1_eval<0><<<1024, 256, 0, stream>>>(x, W1F, cb1, ST + S1, BL);
  conv1_comb2<<<4, 256, 0, stream>>>(BL, ST + S1, 0);
  conv1_eval<1><<<1024, 256, 0, stream>>>(x, W1F, cb1, ST + S1, BL);
  conv1_comb2<<<4, 256, 0, stream>>>(BL, ST + S1, 1);
  conv1_binz<<<1024, 256, 0, stream>>>(x, W1F, cb1, ST + S1, g1, be1, A + A1);

  // binary conv stack: halo variant L2-L5 (bounds 256,6), swizzled pred L6
  conv_bin_halo<2, 2, 32, 128, 8><<<dim3(256, 16), 256, 0, stream>>>(A + A1, W + WC2, CT + CT2, PRE);
  conv_stats<256><<<128, 256, 0, stream>>>(PRE, cb2, ST + S2, 128);
  bin2d<<<512, 256, 0, stream>>>(PRE, ST + S2, cb2, g2, be2, A + A2, 128, 16);

  conv_bin_halo<2, 1, 16, 256, 8><<<dim3(256, 32), 256, 0, stream>>>(A + A2, W + WC3, CT + CT3, PRE);
  conv_stats<256><<<256, 256, 0, stream>>>(PRE, cb3, ST + S3, 256);
  bin2d<<<1024, 256, 0, stream>>>(PRE, ST + S3, cb3, g3, be3, A + A3, 256, 16);

  conv_bin_halo<4, 2, 16, 256, 4><<<dim3(256, 16), 256, 0, stream>>>(A + A3, W + WC4, CT + CT4, PRE);
  conv_stats<64><<<256, 256, 0, stream>>>(PRE, cb4, ST + S4, 256);
  bin2d<<<256, 256, 0, stream>>>(PRE, ST + S4, cb4, g4, be4, A + A4, 256, 8);

  conv_bin_halo<4, 1, 8, 512, 8><<<dim3(256, 16), 256, 0, stream>>>(A + A4, W + WC5, CT + CT5, PRE);
  conv_stats<64><<<512, 256, 0, stream>>>(PRE, cb5, ST + S5, 512);
  bin2d<<<512, 256, 0, stream>>>(PRE, ST + S5, cb5, g5, be5, A + A5, 512, 8);

  conv_bin_pred<8, 2, 8, 512, 4><<<dim3(256, 8), 256, 0, stream>>>(A + A5, W + WC6, PRE);
  conv_stats<16><<<512, 256, 0, stream>>>(PRE, cb6, ST + S6, 512);
  bin2d<<<128, 256, 0, stream>>>(PRE, ST + S6, cb6, g6, be6, A + A6, 512, 4);

  // fc stack (fc1 via transposed activations; fc3 fused)
  transpose_act<<<128, 256, 0, stream>>>(A + A6, AT6);
  fc_layer_t<<<1024, 256, 0, stream>>>(AT6, W + WF1, PRE);
  fc_stats<<<16, 64, 0, stream>>>(PRE, fb1, ST + SF1, 1024);
  fc_bin<<<1024, 256, 0, stream>>>(PRE, ST + SF1, fb1, gf1, bef1, A + AF1, 1024);

  fc_layer<<<1024, 256, 0, stream>>>(A + AF1, W + WF2, PRE, 16, 1024);
  fc_stats<<<16, 64, 0, stream>>>(PRE, fb2, ST + SF2, 1024);
  fc_bin<<<1024, 256, 0, stream>>>(PRE, ST + SF2, fb2, gf2, bef2, A + AF2, 1024);

  fc3_fused<<<1, 256, 0, stream>>>(A + AF2, W + WF3, fb3, gf3, bef3, out);
}

// Round 14
// 986.491 us; speedup vs baseline: 1.0289x; 1.0289x over previous
//
#include <hip/hip_runtime.h>

using u64 = unsigned long long;
typedef __attribute__((ext_vector_type(8))) short vshort8;

// ---------------------------------------------------------------------------
// CIFAR10 BinaryNet, f32-faithful edition (R21: per-layer halo launch bounds
// -- L4 back to (256,3), L2/L3/L5 keep (256,6)).
// Correctness contract (R4-R20 passed absmax 0.0): replicate the np-f32
// reference bit-exactly where signs are decided:
//  * bin_act/bin_w literally: rint(clip((x+1)/2,0,1)) != 0, f32, half-even
//  * conv1: f32 accumulation in (ci,ky,kx) sequential order + bias in f32
//  * binary layers: exact integer dot (XOR+POPCNT), order-independent
//  * BN mean/var: numpy reduction replicated; bn chain in f32
// R20 POST-MORTEM (total 1015.0, +10): SPLIT RESULT. L4 at (256,6) SPILLED
// (VGPR 40, FETCH 152 MB / WRITE 321 MB, dur ~90->118; 5th family spill --
// the "budget 85 > chosen 48" safety argument was WRONG: the allocator
// squeezes under any bound). But L4's +28 vs total +10 => L2/L3/L5 at
// (256,6) collectively GAINED ~18 us (L2 below the 117 cutoff for the first
// time since R11: occupancy hypothesis CONFIRMED for non-spilling layers).
// R21: MINW template param -- L4=(256,3) known-good, L2/L3/L5=(256,6).
// Tripwires: L4 FETCH > 10 MB => squeeze follows NCPB, try (256,4) next;
// absmax stays 0.0. L6 pred + swizzle unchanged (R19-confirmed).
// Activations packed [n][h][w][C/64] u64, bit c%64 of word c/64 == (+1).
// ---------------------------------------------------------------------------

// literal bin_act / bin_w: returns 1 for +1, 0 for -1
__device__ __forceinline__ int bin01(float x) {
  float u = (x + 1.0f) * 0.5f;
  u = fminf(fmaxf(u, 0.0f), 1.0f);
  return rintf(u) != 0.0f;  // round half-even, tie -> 0 -> -1
}

// ============================ weight packing ===============================
// Block per cout; stage the contiguous Cin*9-float row in LDS (coalesced
// float4), pack words from LDS. Same bin01, bit map, out layout => bit-exact.
__global__ void pack_conv_w2(const float* __restrict__ w, u64* __restrict__ out,
                             int Cin) {
  const int co = blockIdx.x;
  const int t = threadIdx.x;  // 256
  const int nf = Cin * 9;     // <= 4608
  __shared__ float ls[4608];
  const float* wr = w + (size_t)co * nf;
  const int nf4 = nf >> 2;
  for (int i = t; i < nf4; i += 256)
    *reinterpret_cast<float4*>(&ls[i * 4]) =
        *reinterpret_cast<const float4*>(&wr[i * 4]);
  __syncthreads();
  const int cqn = Cin >> 6;
  for (int idx = t; idx < 9 * cqn; idx += 256) {
    const int q = idx % cqn, k = idx / cqn;
    u64 word = 0;
    for (int l = 0; l < 64; ++l)
      if (bin01(ls[(q * 64 + l) * 9 + k])) word |= (1ull << l);
    out[(size_t)co * 9 * cqn + idx] = word;
  }
}

// border-pattern correction table: CT[co][p], p = r*3+c, r/c in {0 none,
// 1 first-row/col invalid, 2 last-row/col invalid}. corr = sum of
// popcount(w) over taps in the invalid set (row-set UNION col-set).
__global__ void pack_corr(const u64* __restrict__ W, int* __restrict__ CT) {
  const int idx = blockIdx.x * 256 + threadIdx.x;  // 14976 total
  const int b1 = 1152, b2 = 3456, b3 = 5760, b4 = 10368, b5 = 14976;
  if (idx >= b5) return;
  int lo, woff, cq;
  if (idx < b1)      { lo = 0;  woff = 0;     cq = 2; }   // L2: 128 co
  else if (idx < b2) { lo = b1; woff = 2304;  cq = 2; }   // L3: 256 co
  else if (idx < b3) { lo = b2; woff = 6912;  cq = 4; }   // L4: 256 co
  else if (idx < b4) { lo = b3; woff = 16128; cq = 4; }   // L5: 512 co
  else               { lo = b4; woff = 34560; cq = 8; }   // L6: 512 co
  const int rel = idx - lo;
  const int co = rel / 9, p = rel % 9;
  const int r = p / 3, c = p % 3;
  int corr = 0;
  for (int dy = 0; dy < 3; ++dy)
    for (int dx = 0; dx < 3; ++dx) {
      const bool inv = (r == 1 && dy == 0) || (r == 2 && dy == 2) ||
                       (c == 1 && dx == 0) || (c == 2 && dx == 2);
      if (inv) {
        const u64* wp = W + woff + ((size_t)(co * 9 + dy * 3 + dx)) * cq;
        for (int q = 0; q < cq; ++q) corr += __popcll(wp[q]);
      }
    }
  CT[idx] = corr;
}

__global__ void pack_fc_w(const float* __restrict__ w, u64* __restrict__ out,
                          int Fi, int Fo) {
  const int fiq = Fi >> 6;
  const int total = Fo * fiq;
  const int idx = blockIdx.x * 256 + threadIdx.x;
  if (idx >= total) return;
  const int q = idx % fiq, o = idx / fiq;
  u64 word = 0;
  for (int l = 0; l < 64; ++l)
    if (bin01(w[(size_t)o * Fi + q * 64 + l])) word |= (1ull << l);
  out[idx] = word;
}

// fc1 with NCHW-flatten permutation: f = c*16 + h*4 + w; act word q=(h*4+w)*8+cq
// One o-row (8192 floats, 32 KB) staged in LDS coalesced; 128 threads pack.
__global__ void pack_fc1_w(const float* __restrict__ w, u64* __restrict__ out) {
  const int o = blockIdx.x;  // 1024
  const int t = threadIdx.x; // 256
  __shared__ float ls[8192];
  const float* wr = w + (size_t)o * 8192;
  for (int i = t; i < 2048; i += 256)
    *reinterpret_cast<float4*>(&ls[i * 4]) =
        *reinterpret_cast<const float4*>(&wr[i * 4]);
  __syncthreads();
  if (t < 128) {
    const int q = t, cq = q & 7, hw = q >> 3;
    u64 word = 0;
    for (int l = 0; l < 64; ++l) {
      const int f = (cq * 64 + l) * 16 + hw;
      if (bin01(ls[f])) word |= (1ull << l);
    }
    out[(size_t)o * 128 + q] = word;
  }
}

// conv1 weight signs as +-1.0f floats (k = ci*9+dy*3+dx), for uniform s_load
__global__ void pack_w1f(const float* __restrict__ w1, float* __restrict__ w1f) {
  const int i = blockIdx.x * 256 + threadIdx.x;  // 3456
  if (i < 3456) w1f[i] = bin01(w1[i]) ? 1.0f : -1.0f;
}

// ============================== conv1 (f32) ================================
__device__ __forceinline__ void stage_image(const float* __restrict__ x, int n,
                                            float* __restrict__ xs, int nthreads,
                                            int t) {
  for (int idx = t; idx < 3 * 34 * 34; idx += nthreads) {
    const int ci = idx / 1156, rem = idx % 1156;
    const int hy = rem / 34, wx = rem % 34;
    float v = 0.0f;
    if (hy >= 1 && hy <= 32 && wx >= 1 && wx <= 32)
      v = x[(size_t)n * 3072 + ci * 1024 + (hy - 1) * 32 + (wx - 1)];
    xs[idx] = v;
  }
}

// eval + leaf-sum kernel. block = (n, quarter q); thread = position p (256).
template <int PASS>
__global__ void conv1_eval(const float* __restrict__ x,
                           const float* __restrict__ w1f,
                           const float* __restrict__ cb,
                           const float* __restrict__ st,
                           float* __restrict__ BL) {
  const int blk = blockIdx.x;  // n*4 + q
  const int n = blk >> 2, q = blk & 3;
  const int t = threadIdx.x;   // 256
  __shared__ float xs[3 * 34 * 34];
  __shared__ float yl[256 * 8];    // [p][j8]
  __shared__ float rl[2 * 8 * 8];  // [L][c8][j]
  stage_image(x, n, xs, 256, t);
  __syncthreads();
  const int hw = q * 256 + t;
  const int h = hw >> 5, w = hw & 31;
  float win[27];
#pragma unroll
  for (int k = 0; k < 27; ++k) {
    const int ci = k / 9, dy = (k % 9) / 3, dx = k % 3;
    win[k] = xs[ci * 1156 + (h + dy) * 34 + (w + dx)];
  }
  for (int cc = 0; cc < 16; ++cc) {  // 8 channels per chunk
    float y8[8];
#pragma unroll
    for (int j8 = 0; j8 < 8; ++j8) {
      const int c = cc * 8 + j8;
      const float* wp = w1f + c * 27;
      float acc = 0.0f;
#pragma unroll
      for (int k = 0; k < 27; ++k) acc = fmaf(wp[k], win[k], acc);
      float y = acc + cb[c];
      if (PASS) { const float d = y - st[2 * c]; y = d * d; }
      y8[j8] = y;
    }
    __syncthreads();  // previous chunk's readers done
#pragma unroll
    for (int j8 = 0; j8 < 8; ++j8) yl[t * 8 + j8] = y8[j8];
    __syncthreads();
    if (t < 128) {  // numpy 8-accumulator pass: r = sum_i y[i*8+j], i sequential
      const int L = t >> 6, j = (t >> 3) & 7, c8 = t & 7;
      float r = yl[(L * 128 + j) * 8 + c8];
      for (int i = 1; i < 16; ++i) r += yl[(L * 128 + i * 8 + j) * 8 + c8];
      rl[(L * 8 + c8) * 8 + j] = r;
    }
    __syncthreads();
    if (t < 16) {  // 8-way tree combine, write leaf sum
      const int L = t >> 3, c8 = t & 7;
      const float* p = rl + (L * 8 + c8) * 8;
      const float s =
          ((p[0] + p[1]) + (p[2] + p[3])) + ((p[4] + p[5]) + (p[6] + p[7]));
      BL[((size_t)(n * 8) + (q * 2 + L)) * 128 + (cc * 8 + c8)] = s;
    }
  }
}

// leaf-pairwise then batch-sequential combine (numpy multi-axis reduce order).
__global__ void conv1_comb2(const float* __restrict__ BL, float* __restrict__ st,
                            int pass) {
  const int t = threadIdx.x;        // 256
  const int lane = t & 63;
  const int wid = t >> 6;           // 4 waves
  const int c = blockIdx.x * 32 + wid * 8 + (lane & 7);  // 4 blocks -> 128 ch
  const int leaf = lane >> 3;       // 0..7
  const float* base = BL + (size_t)leaf * 128 + c;
  float S = 0.0f;
#pragma unroll 4
  for (int n = 0; n < 256; ++n) {
    const float v = base[(size_t)n * 1024];
    const float a = v + __shfl_xor(v, 8);    // (l0+l1) etc.
    const float b = a + __shfl_xor(a, 16);   // (l0+l1)+(l2+l3)
    const float Ln = b + __shfl_xor(b, 32);  // full 8-way tree
    S = (n == 0) ? Ln : (S + Ln);
  }
  if (leaf == 0) {
    if (pass == 0) st[2 * c] = S / 262144.0f;
    else           st[2 * c + 1] = 1.0f / sqrtf(S / 262144.0f + 1e-4f);
  }
}

// binarize: thread = position; loops all 128 channels with register window,
// packs bits per-thread (bit l of word cq <-> c = cq*64+l).
__global__ void conv1_binz(const float* __restrict__ x,
                           const float* __restrict__ w1f,
                           const float* __restrict__ cb,
                           const float* __restrict__ st,
                           const float* __restrict__ g,
                           const float* __restrict__ be,
                           u64* __restrict__ out) {
  const int blk = blockIdx.x;  // n*4 + q
  const int n = blk >> 2, q = blk & 3;
  const int t = threadIdx.x;   // 256
  __shared__ float xs[3 * 34 * 34];
  stage_image(x, n, xs, 256, t);
  __syncthreads();
  const int hw = q * 256 + t;
  const int h = hw >> 5, w = hw & 31;
  float win[27];
#pragma unroll
  for (int k = 0; k < 27; ++k) {
    const int ci = k / 9, dy = (k % 9) / 3, dx = k % 3;
    win[k] = xs[ci * 1156 + (h + dy) * 34 + (w + dx)];
  }
  u64 m0 = 0, m1 = 0;
  for (int c = 0; c < 128; ++c) {
    const float* wp = w1f + c * 27;
    float acc = 0.0f;
#pragma unroll
    for (int k = 0; k < 27; ++k) acc = fmaf(wp[k], win[k], acc);
    const float y = acc + cb[c];
    const float tv = ((y - st[2 * c]) * st[2 * c + 1]) * g[c] + be[c];
    const u64 bit = (u64)bin01(tv);
    if (c < 64) m0 |= bit << c;
    else        m1 |= bit << (c - 64);
  }
  u64* dst = out + ((size_t)(n * 1024 + hw)) * 2;
  dst[0] = m0;
  dst[1] = m1;
}

// ================== halo zeroing helper (conv_bin_halo) ====================
template <int CQ, int H>
__device__ __forceinline__ void zero_halo(u64* __restrict__ xs, int t) {
  constexpr int HP = H + 2;
  constexpr int HALO = 2 * HP * CQ + 2 * H * CQ;
  for (int j = t; j < HALO; j += 256) {
    int widx;
    if (j < HP * CQ) widx = j;                                  // row 0
    else if (j < 2 * HP * CQ) widx = (H + 1) * HP * CQ + (j - HP * CQ);  // row H+1
    else {
      const int r = j - 2 * HP * CQ;          // 0 .. 2*H*CQ-1
      const int row = (r / (2 * CQ)) + 1;     // 1..H (2*CQ pow2 -> shift)
      const int s = r & (2 * CQ - 1);
      const int col = (s < CQ) ? 0 : (HP - 1);
      widx = (row * HP + col) * CQ + (s & (CQ - 1));
    }
    xs[widx] = 0;
  }
}

// ================= binary conv, halo variant (L2-L5 only) ==================
// Zero-halo LDS tile, unconditional bcnt-accumulate, CT-corrected integer dot
// (exact). R21: MINW template param. L2/L3/L5 = 6 (R20-measured gain);
// L4 = 3 (R20 spill at 6: VGPR 40, 485 MB HBM -> revert to known-good).
template <int CQ, int POOL, int H, int COUT, int NCPB, int MINW>
__launch_bounds__(256, MINW)
__global__ void conv_bin_halo(const u64* __restrict__ xin, const u64* __restrict__ wpk,
                              const int* __restrict__ ct, short* __restrict__ pre) {
  constexpr int OH = H / POOL;
  constexpr int PLANE = OH * OH;
  constexpr int G = 256 / PLANE;
  constexpr int NE = POOL * POOL;
  constexpr int HP = H + 2;
  constexpr int NWP = HP * HP * CQ;
  constexpr int QC = (CQ > 4) ? 4 : CQ;
  constexpr int NQC = CQ / QC;
  constexpr int IW = H * H * CQ;   // interior word count
  constexpr int VEC = IW / 256;    // words per thread (8/2/4/1), VEC | CQ*H
  const int n = blockIdx.x;
  const int t = threadIdx.x;
  __shared__ __align__(16) u64 xs[NWP];
  const u64* src = xin + (size_t)n * IW;
  {
    const int i0 = t * VEC;
    const int q0 = i0 & (CQ - 1);
    const int w0 = (i0 / CQ) & (H - 1);
    const int h0 = i0 / (CQ * H);
    const int dst0 = ((h0 + 1) * HP + (w0 + 1)) * CQ + q0;
    if constexpr (VEC >= 2) {
      ulonglong2 tmp[VEC / 2];
#pragma unroll
      for (int v = 0; v < VEC / 2; ++v)
        tmp[v] = *reinterpret_cast<const ulonglong2*>(&src[i0 + 2 * v]);
      zero_halo<CQ, H>(xs, t);  // overlaps with in-flight loads
#pragma unroll
      for (int v = 0; v < VEC / 2; ++v)
        *reinterpret_cast<ulonglong2*>(&xs[dst0 + 2 * v]) = tmp[v];
    } else {
      const u64 tv = src[i0];
      zero_halo<CQ, H>(xs, t);
      xs[dst0] = tv;
    }
  }
  __syncthreads();
  int cosub;
  if constexpr (PLANE >= 64) cosub = __builtin_amdgcn_readfirstlane(t / PLANE);
  else cosub = t / PLANE;
  const int pos = t % PLANE;
  const int oh = pos / OH, ow = pos % OH;

  int cbase[NE];
#pragma unroll
  for (int py = 0; py < POOL; ++py)
#pragma unroll
    for (int px = 0; px < POOL; ++px)
      cbase[py * POOL + px] = ((oh * POOL + py) * HP + (ow * POOL + px)) * CQ;

  int pc[NCPB][NE];
#pragma unroll
  for (int cc = 0; cc < NCPB; ++cc)
#pragma unroll
    for (int e = 0; e < NE; ++e) pc[cc][e] = 0;

#pragma unroll
  for (int qc = 0; qc < NQC; ++qc) {
#pragma unroll
    for (int k = 0; k < 9; ++k) {
      const int dy = k / 3, dx = k % 3;
      const int koff = (dy * HP + dx) * CQ + qc * QC;  // compile-time per (k,qc)
      u64 cw[NE][QC];
#pragma unroll
      for (int e = 0; e < NE; ++e) {
        const u64* cp = &xs[cbase[e] + koff];
#pragma unroll
        for (int q = 0; q < QC; ++q) cw[e][q] = cp[q];
      }
#pragma unroll
      for (int cc = 0; cc < NCPB; ++cc) {
        const int co = (blockIdx.y * NCPB + cc) * G + cosub;
        const u64* wp = wpk + ((size_t)co * 9 + k) * CQ + qc * QC;
        u64 w[QC];
#pragma unroll
        for (int q = 0; q < QC; ++q) w[q] = wp[q];
#pragma unroll
        for (int e = 0; e < NE; ++e) {
          int acc = pc[cc][e];
#pragma unroll
          for (int q = 0; q < QC; ++q) acc += __popcll(cw[e][q] ^ w[q]);
          pc[cc][e] = acc;
        }
      }
    }
  }

  int vcnt[NE];
#pragma unroll
  for (int py = 0; py < POOL; ++py) {
#pragma unroll
    for (int px = 0; px < POOL; ++px) {
      int cvn = 0;
#pragma unroll
      for (int dy = 0; dy < 3; ++dy)
#pragma unroll
        for (int dx = 0; dx < 3; ++dx) {
          const int hh = oh * POOL + py + dy - 1, ww = ow * POOL + px + dx - 1;
          cvn += (((unsigned)hh < (unsigned)H) && ((unsigned)ww < (unsigned)H)) ? 1 : 0;
        }
      vcnt[py * POOL + px] = cvn;
    }
  }
  int cofs[NE];
#pragma unroll
  for (int py = 0; py < POOL; ++py)
#pragma unroll
    for (int px = 0; px < POOL; ++px) {
      const int chh = oh * POOL + py, cww = ow * POOL + px;
      const int rr = (chh == 0) ? 1 : ((chh == H - 1) ? 2 : 0);
      const int cl = (cww == 0) ? 1 : ((cww == H - 1) ? 2 : 0);
      cofs[py * POOL + px] = rr * 3 + cl;
    }
#pragma unroll
  for (int cc = 0; cc < NCPB; ++cc) {
    const int co = (blockIdx.y * NCPB + cc) * G + cosub;
    const int* ctp = ct + co * 9;
    int best = -1000000;
#pragma unroll
    for (int e = 0; e < NE; ++e) {
      const int dot = vcnt[e] * (CQ * 64) - 2 * (pc[cc][e] - ctp[cofs[e]]);
      best = dot > best ? dot : best;
    }
    pre[((size_t)(n * COUT + co) * OH + oh) * OH + ow] = (short)best;
  }
}

// ============== binary conv, predicated variant (L6 only) ==================
// R19 swizzle CONFIRMED: group-granular XOR kills the 16-way pos-group
// conflict. Unchanged.
template <int CQ, int POOL, int H, int COUT, int NCPB>
__launch_bounds__(256, 4)
__global__ void conv_bin_pred(const u64* __restrict__ xin, const u64* __restrict__ wpk,
                              short* __restrict__ pre) {
  constexpr int OH = H / POOL;
  constexpr int PLANE = OH * OH;
  constexpr int G = 256 / PLANE;
  constexpr int NE = POOL * POOL;
  constexpr int NW_ = H * H * CQ;
  constexpr int QC = (CQ > 4) ? 4 : CQ;
  constexpr int NQC = CQ / QC;
  constexpr bool SWZ = (CQ == 8 && H == 8 && POOL == 2);  // bit layout assumption
  const int n = blockIdx.x;
  const int t = threadIdx.x;
  __shared__ u64 xs[NW_];
  const u64* src = xin + (size_t)n * NW_;
  for (int i = t; i < NW_; i += 256) {
    int di = i;
    if constexpr (SWZ) {
      const int g = i >> 2;
      const int gs = g ^ ((g >> 5) & 1) ^ (((g >> 2) & 1) << 1);
      di = (gs << 2) | (i & 3);
    }
    xs[di] = src[i];
  }
  __syncthreads();
  const int cosub = t / PLANE;
  const int pos = t % PLANE;
  const int oh = pos / OH, ow = pos % OH;

  int pc[NCPB][NE];
#pragma unroll
  for (int cc = 0; cc < NCPB; ++cc)
#pragma unroll
    for (int e = 0; e < NE; ++e) pc[cc][e] = 0;

#pragma unroll
  for (int qc = 0; qc < NQC; ++qc) {
#pragma unroll
    for (int k = 0; k < 9; ++k) {
      const int dy = k / 3, dx = k % 3;
      u64 cw[NE][QC];
      bool cv[NE];
#pragma unroll
      for (int py = 0; py < POOL; ++py) {
#pragma unroll
        for (int px = 0; px < POOL; ++px) {
          const int hh = oh * POOL + py + dy - 1;
          const int ww = ow * POOL + px + dx - 1;
          const bool v = ((unsigned)hh < (unsigned)H) && ((unsigned)ww < (unsigned)H);
          const int e = py * POOL + px;
          cv[e] = v;
          int base = v ? ((hh * H + ww) * CQ + qc * QC) : 0;
          if constexpr (SWZ) {
            const int g = base >> 2;
            const int gs = g ^ ((g >> 5) & 1) ^ (((g >> 2) & 1) << 1);
            base = gs << 2;  // QC==4: base is group-aligned; q-order preserved
          }
#pragma unroll
          for (int q = 0; q < QC; ++q) cw[e][q] = xs[base + q];
        }
      }
#pragma unroll
      for (int cc = 0; cc < NCPB; ++cc) {
        const int co = (blockIdx.y * NCPB + cc) * G + cosub;
        const u64* wp = wpk + ((size_t)co * 9 + k) * CQ + qc * QC;
        u64 w[QC];
#pragma unroll
        for (int q = 0; q < QC; ++q) w[q] = wp[q];
#pragma unroll
        for (int e = 0; e < NE; ++e) {
          int tp = 0;
#pragma unroll
          for (int q = 0; q < QC; ++q) tp += __popcll(cw[e][q] ^ w[q]);
          pc[cc][e] += cv[e] ? tp : 0;
        }
      }
    }
  }

  int vcnt[NE];
#pragma unroll
  for (int py = 0; py < POOL; ++py) {
#pragma unroll
    for (int px = 0; px < POOL; ++px) {
      int cvn = 0;
#pragma unroll
      for (int dy = 0; dy < 3; ++dy)
#pragma unroll
        for (int dx = 0; dx < 3; ++dx) {
          const int hh = oh * POOL + py + dy - 1, ww = ow * POOL + px + dx - 1;
          cvn += (((unsigned)hh < (unsigned)H) && ((unsigned)ww < (unsigned)H)) ? 1 : 0;
        }
      vcnt[py * POOL + px] = cvn;
    }
  }
#pragma unroll
  for (int cc = 0; cc < NCPB; ++cc) {
    const int co = (blockIdx.y * NCPB + cc) * G + cosub;
    int best = -1000000;
#pragma unroll
    for (int e = 0; e < NE; ++e) {
      const int dot = vcnt[e] * (CQ * 64) - 2 * pc[cc][e];
      best = dot > best ? dot : best;
    }
    pre[((size_t)(n * COUT + co) * OH + oh) * OH + ow] = (short)best;
  }
}

// ======================= BN stats, numpy-faithful ==========================
// short8 vector loads -- the numpy 8-accumulator block is exactly 8
// consecutive shorts; identical adds in identical order => bit-exact.
template <int PASS>
__device__ __forceinline__ float acc8(const short* __restrict__ p, float b, float m,
                                      int start, int len) {
  float r[8];
  const vshort8 v0 = *reinterpret_cast<const vshort8*>(&p[start]);
#pragma unroll
  for (int j = 0; j < 8; ++j) {
    float y = (float)v0[j] + b;
    if (PASS) { const float d = y - m; y = d * d; }
    r[j] = y;
  }
  for (int i = 8; i < len; i += 8) {
    const vshort8 vi = *reinterpret_cast<const vshort8*>(&p[start + i]);
#pragma unroll
    for (int j = 0; j < 8; ++j) {
      float y = (float)vi[j] + b;
      if (PASS) { const float d = y - m; y = d * d; }
      r[j] += y;
    }
  }
  return ((r[0] + r[1]) + (r[2] + r[3])) + ((r[4] + r[5]) + (r[6] + r[7]));
}

template <int PASS>
__device__ __forceinline__ float np_sum_hw(const short* __restrict__ p, float b,
                                           float m, int HW) {
  if (HW == 256) return acc8<PASS>(p, b, m, 0, 128) + acc8<PASS>(p, b, m, 128, 128);
  return acc8<PASS>(p, b, m, 0, HW);  // HW = 16 or 64
}

template <int HW>
__global__ void conv_stats(const short* __restrict__ pre, const float* __restrict__ cb,
                           float* __restrict__ st, int Cout) {
  const int c = blockIdx.x;
  const int n = threadIdx.x;  // 256
  const float b = cb[c];
  const short* p = pre + ((size_t)n * Cout + c) * HW;
  __shared__ float ls[256];
  ls[n] = np_sum_hw<0>(p, b, 0.0f, HW);
  __syncthreads();
  __shared__ float ms;
  if (n == 0) {
    float S = ls[0];
    for (int i = 1; i < 256; ++i) S += ls[i];
    ms = S / (float)(256 * HW);
  }
  __syncthreads();
  const float m = ms;
  __syncthreads();
  ls[n] = np_sum_hw<1>(p, b, m, HW);
  __syncthreads();
  if (n == 0) {
    float S = ls[0];
    for (int i = 1; i < 256; ++i) S += ls[i];
    const float v = S / (float)(256 * HW);
    st[2 * c] = m;
    st[2 * c + 1] = 1.0f / sqrtf(v + 1e-4f);
  }
}

// =========================== binarize 2d / pack ============================
__global__ void bin2d(const short* __restrict__ pre, const float* __restrict__ st,
                      const float* __restrict__ cb, const float* __restrict__ g,
                      const float* __restrict__ be, u64* __restrict__ out,
                      int Cout, int OH) {
  const int CQ = Cout >> 6;
  const int HW = OH * OH;
  const int widx = blockIdx.x * 256 + threadIdx.x;  // (n*CQ+cq)*HW+hw
  const int hw = widx % HW;
  const int r = widx / HW;
  const int cq = r % CQ;
  const int n = r / CQ;
  const short* p = pre + ((size_t)(n * Cout + cq * 64)) * HW + hw;
  u64 mask = 0;
  for (int c = 0; c < 64; ++c) {
    const int ch = cq * 64 + c;
    const float val = (float)p[(size_t)c * HW] + cb[ch];
    const float tv = ((val - st[2 * ch]) * st[2 * ch + 1]) * g[ch] + be[ch];
    mask |= ((u64)bin01(tv)) << c;
  }
  out[((size_t)n * HW + hw) * CQ + cq] = mask;
}

// ================== fc1 activation transpose =========================
__global__ void transpose_act(const u64* __restrict__ a, u64* __restrict__ at) {
  const int widx = blockIdx.x * 256 + threadIdx.x;  // 32768 = 256n x 128q
  const int n = widx >> 7, q = widx & 127;
  at[(size_t)q * 256 + n] = a[widx];
}

// ================================ fc layers ================================
__global__ void fc_layer_t(const u64* __restrict__ at, const u64* __restrict__ wpk,
                           short* __restrict__ pre) {
  const int o = blockIdx.x;   // 1024
  const int n = threadIdx.x;  // 256
  const u64* wp = wpk + (size_t)o * 128;
  int pc = 0;
#pragma unroll 8
  for (int q = 0; q < 128; ++q) pc += __popcll(at[(size_t)q * 256 + n] ^ wp[q]);
  pre[(size_t)n * 1024 + o] = (short)(8192 - 2 * pc);
}

__global__ void fc_layer(const u64* __restrict__ xin, const u64* __restrict__ wpk,
                         short* __restrict__ pre, int FiQ, int Fo) {
  const int o = blockIdx.x;
  const int n = threadIdx.x;  // 256
  const u64* xp = xin + (size_t)n * FiQ;
  const u64* wp = wpk + (size_t)o * FiQ;
  int pc = 0;
  for (int q = 0; q < FiQ; ++q) pc += __popcll(xp[q] ^ wp[q]);
  pre[(size_t)n * Fo + o] = (short)(FiQ * 64 - 2 * pc);
}

__global__ void fc_stats(const short* __restrict__ pre, const float* __restrict__ fb,
                         float* __restrict__ st, int Fo) {
  const int o = blockIdx.x * blockDim.x + threadIdx.x;
  if (o >= Fo) return;
  const float b = fb[o];
  float S = (float)pre[o] + b;
#pragma unroll 8
  for (int n = 1; n < 256; ++n) S += (float)pre[(size_t)n * Fo + o] + b;
  const float m = S / 256.0f;
  float d0 = (float)pre[o] + b - m;
  float V = d0 * d0;
#pragma unroll 8
  for (int n = 1; n < 256; ++n) {
    const float d = (float)pre[(size_t)n * Fo + o] + b - m;
    V += d * d;
  }
  st[2 * o] = m;
  st[2 * o + 1] = 1.0f / sqrtf(V / 256.0f + 1e-4f);
}

__global__ void fc_bin(const short* __restrict__ pre, const float* __restrict__ st,
                       const float* __restrict__ fb, const float* __restrict__ g,
                       const float* __restrict__ be, u64* __restrict__ out, int Fo) {
  const int gid = blockIdx.x * 4 + (threadIdx.x >> 6);
  const int lane = threadIdx.x & 63;
  const int OQ = Fo >> 6;
  const int oq = gid % OQ, n = gid / OQ;
  const int o = oq * 64 + lane;
  const float val = (float)pre[(size_t)n * Fo + o] + fb[o];
  const float tv = ((val - st[2 * o]) * st[2 * o + 1]) * g[o] + be[o];
  const u64 mask = __ballot(bin01(tv));
  if (lane == 0) out[(size_t)n * OQ + oq] = mask;
}

// fc3 layer + stats + output fused into one 1-block kernel. Same popcnt
// integer dot; stats replicate fc_stats' exact sequential-n f32 order; output
// expression identical to fc_out.
__global__ void fc3_fused(const u64* __restrict__ xin, const u64* __restrict__ wpk,
                          const float* __restrict__ fb, const float* __restrict__ g,
                          const float* __restrict__ be, float* __restrict__ out) {
  const int n = threadIdx.x;  // 256
  __shared__ short lpre[2560];
  __shared__ float st[20];
  u64 xw[16];
  const u64* xp = xin + (size_t)n * 16;
#pragma unroll
  for (int q = 0; q < 16; ++q) xw[q] = xp[q];
  for (int o = 0; o < 10; ++o) {
    const u64* wp = wpk + (size_t)o * 16;
    int pc = 0;
#pragma unroll
    for (int q = 0; q < 16; ++q) pc += __popcll(xw[q] ^ wp[q]);
    lpre[n * 10 + o] = (short)(1024 - 2 * pc);
  }
  __syncthreads();
  if (n < 10) {
    const float b = fb[n];
    float S = (float)lpre[n] + b;
    for (int i = 1; i < 256; ++i) S += (float)lpre[i * 10 + n] + b;
    const float m = S / 256.0f;
    float d0 = (float)lpre[n] + b - m;
    float V = d0 * d0;
    for (int i = 1; i < 256; ++i) {
      const float d = (float)lpre[i * 10 + n] + b - m;
      V += d * d;
    }
    st[2 * n] = m;
    st[2 * n + 1] = 1.0f / sqrtf(V / 256.0f + 1e-4f);
  }
  __syncthreads();
  for (int o = 0; o < 10; ++o) {
    const float val = (float)lpre[n * 10 + o] + fb[o];
    out[n * 10 + o] = ((val - st[2 * o]) * st[2 * o + 1]) * g[o] + be[o];
  }
}

// ================================= launch ==================================
extern "C" void kernel_launch(void* const* d_in, const int* in_sizes, int n_in,
                              void* d_out, int out_size, void* d_ws, size_t ws_size,
                              hipStream_t stream) {
  if (n_in < 37) return;
  const float* x = (const float*)d_in[0];
  const float *cw1 = (const float*)d_in[1],  *cb1 = (const float*)d_in[2],  *g1 = (const float*)d_in[3],  *be1 = (const float*)d_in[4];
  const float *cw2 = (const float*)d_in[5],  *cb2 = (const float*)d_in[6],  *g2 = (const float*)d_in[7],  *be2 = (const float*)d_in[8];
  const float *cw3 = (const float*)d_in[9],  *cb3 = (const float*)d_in[10], *g3 = (const float*)d_in[11], *be3 = (const float*)d_in[12];
  const float *cw4 = (const float*)d_in[13], *cb4 = (const float*)d_in[14], *g4 = (const float*)d_in[15], *be4 = (const float*)d_in[16];
  const float *cw5 = (const float*)d_in[17], *cb5 = (const float*)d_in[18], *g5 = (const float*)d_in[19], *be5 = (const float*)d_in[20];
  const float *cw6 = (const float*)d_in[21], *cb6 = (const float*)d_in[22], *g6 = (const float*)d_in[23], *be6 = (const float*)d_in[24];
  const float *fw1 = (const float*)d_in[25], *fb1 = (const float*)d_in[26], *gf1 = (const float*)d_in[27], *bef1 = (const float*)d_in[28];
  const float *fw2 = (const float*)d_in[29], *fb2 = (const float*)d_in[30], *gf2 = (const float*)d_in[31], *bef2 = (const float*)d_in[32];
  const float *fw3 = (const float*)d_in[33], *fb3 = (const float*)d_in[34], *gf3 = (const float*)d_in[35], *bef3 = (const float*)d_in[36];
  float* out = (float*)d_out;

  char* ws = (char*)d_ws;
  if (ws_size < 46137344) return;
  float* ST = (float*)ws;                    // f32 stats (m, 1/sqrt(v+eps)) pairs
  float* W1F = (float*)(ws + 32768);         // conv1 +-1.0f signs, 13824 B
  float* BL = (float*)(ws + 65536);          // conv1 leaf partials [256][8][128], 1 MB
  u64* W = (u64*)(ws + 1179648);             // packed weights, 1752320 B
  u64* A = (u64*)(ws + 2981888);             // packed activations, 9240576 B
  int* CT = (int*)(ws + 12222464);           // border-corr tables, 59904 B
  short* PRE = (short*)(ws + 12582912);      // integer pre-activations (reused)
  u64* AT6 = (u64*)(ws + 33554432);          // fc1 transposed acts, 262144 B
  const int S1 = 0, S2 = 256, S3 = 512, S4 = 1024, S5 = 1536, S6 = 2560;
  const int SF1 = 3584, SF2 = 5632;
  const size_t WC2 = 0, WC3 = 2304, WC4 = 6912, WC5 = 16128, WC6 = 34560;
  const size_t WF1 = 71424, WF2 = 202496, WF3 = 218880;
  const size_t A1 = 0, A2 = 524288, A3 = 655360, A4 = 917504, A5 = 983040;
  const size_t A6 = 1114112, AF1 = 1146880, AF2 = 1150976;
  const int CT2 = 0, CT3 = 1152, CT4 = 3456, CT5 = 5760;

  // pack weights (literal bin_w semantics; block-per-cout LDS-staged)
  pack_w1f<<<14, 256, 0, stream>>>(cw1, W1F);
  pack_conv_w2<<<128, 256, 0, stream>>>(cw2, W + WC2, 128);
  pack_conv_w2<<<256, 256, 0, stream>>>(cw3, W + WC3, 128);
  pack_conv_w2<<<256, 256, 0, stream>>>(cw4, W + WC4, 256);
  pack_conv_w2<<<512, 256, 0, stream>>>(cw5, W + WC5, 256);
  pack_conv_w2<<<512, 256, 0, stream>>>(cw6, W + WC6, 512);
  pack_corr<<<59, 256, 0, stream>>>(W, CT);
  pack_fc1_w<<<1024, 256, 0, stream>>>(fw1, W + WF1);
  pack_fc_w<<<64, 256, 0, stream>>>(fw2, W + WF2, 1024, 1024);
  pack_fc_w<<<1, 256, 0, stream>>>(fw3, W + WF3, 1024, 10);

  // layer 1: position-major f32 conv, numpy-faithful stats, binarize
  conv1_eval<0><<<1024, 256, 0, stream>>>(x, W1F, cb1, ST + S1, BL);
  conv1_comb2<<<4, 256, 0, stream>>>(BL, ST + S1, 0);
  conv1_eval<1><<<1024, 256, 0, stream>>>(x, W1F, cb1, ST + S1, BL);
  conv1_comb2<<<4, 256, 0, stream>>>(BL, ST + S1, 1);
  conv1_binz<<<1024, 256, 0, stream>>>(x, W1F, cb1, ST + S1, g1, be1, A + A1);

  // binary conv stack: halo L2/L3/L5 (256,6), halo L4 (256,3), pred L6
  conv_bin_halo<2, 2, 32, 128, 8, 6><<<dim3(256, 16), 256, 0, stream>>>(A + A1, W + WC2, CT + CT2, PRE);
  conv_stats<256><<<128, 256, 0, stream>>>(PRE, cb2, ST + S2, 128);
  bin2d<<<512, 256, 0, stream>>>(PRE, ST + S2, cb2, g2, be2, A + A2, 128, 16);

  conv_bin_halo<2, 1, 16, 256, 8, 6><<<dim3(256, 32), 256, 0, stream>>>(A + A2, W + WC3, CT + CT3, PRE);
  conv_stats<256><<<256, 256, 0, stream>>>(PRE, cb3, ST + S3, 256);
  bin2d<<<1024, 256, 0, stream>>>(PRE, ST + S3, cb3, g3, be3, A + A3, 256, 16);

  conv_bin_halo<4, 2, 16, 256, 4, 3><<<dim3(256, 16), 256, 0, stream>>>(A + A3, W + WC4, CT + CT4, PRE);
  conv_stats<64><<<256, 256, 0, stream>>>(PRE, cb4, ST + S4, 256);
  bin2d<<<256, 256, 0, stream>>>(PRE, ST + S4, cb4, g4, be4, A + A4, 256, 8);

  conv_bin_halo<4, 1, 8, 512, 8, 6><<<dim3(256, 16), 256, 0, stream>>>(A + A4, W + WC5, CT + CT5, PRE);
  conv_stats<64><<<512, 256, 0, stream>>>(PRE, cb5, ST + S5, 512);
  bin2d<<<512, 256, 0, stream>>>(PRE, ST + S5, cb5, g5, be5, A + A5, 512, 8);

  conv_bin_pred<8, 2, 8, 512, 4><<<dim3(256, 8), 256, 0, stream>>>(A + A5, W + WC6, PRE);
  conv_stats<16><<<512, 256, 0, stream>>>(PRE, cb6, ST + S6, 512);
  bin2d<<<128, 256, 0, stream>>>(PRE, ST + S6, cb6, g6, be6, A + A6, 512, 4);

  // fc stack (fc1 via transposed activations; fc3 fused)
  transpose_act<<<128, 256, 0, stream>>>(A + A6, AT6);
  fc_layer_t<<<1024, 256, 0, stream>>>(AT6, W + WF1, PRE);
  fc_stats<<<16, 64, 0, stream>>>(PRE, fb1, ST + SF1, 1024);
  fc_bin<<<1024, 256, 0, stream>>>(PRE, ST + SF1, fb1, gf1, bef1, A + AF1, 1024);

  fc_layer<<<1024, 256, 0, stream>>>(A + AF1, W + WF2, PRE, 16, 1024);
  fc_stats<<<16, 64, 0, stream>>>(PRE, fb2, ST + SF2, 1024);
  fc_bin<<<1024, 256, 0, stream>>>(PRE, ST + SF2, fb2, gf2, bef2, A + AF2, 1024);

  fc3_fused<<<1, 256, 0, stream>>>(A + AF2, W + WF3, fb3, gf3, bef3, out);
}